// Round 2
// baseline (1473.590 us; speedup 1.0000x reference)
//
#include <hip/hip_runtime.h>
#include <stdint.h>

#define KK_  1024   // inner dim of both GEMMs

typedef __bf16 bf16x8 __attribute__((ext_vector_type(8)));
typedef float  f32x4  __attribute__((ext_vector_type(4)));

__device__ __forceinline__ void cp16(void* lds, const void* g) {
  __builtin_amdgcn_global_load_lds(
      (const __attribute__((address_space(1))) void*)g,
      (__attribute__((address_space(3))) void*)lds, 16, 0, 0);
}

__device__ __forceinline__ float b2f(unsigned short u) {
  union { unsigned int i; float f; } x;
  x.i = ((unsigned int)u) << 16;
  return x.f;
}

__device__ __forceinline__ unsigned short f2b(float f) {
  unsigned int u = __builtin_bit_cast(unsigned int, f);
  unsigned int lsb = (u >> 16) & 1u;
  u += 0x7fffu + lsb;
  return (unsigned short)(u >> 16);
}

// fp32 -> bf16 elementwise, 4 elems/thread. n must be a multiple of 4.
__global__ __launch_bounds__(256) void cvt_f32_bf16(
    const float* __restrict__ src, unsigned short* __restrict__ dst, int n) {
  int i = (blockIdx.x * 256 + threadIdx.x) * 4;
  if (i < n) {
    float4 v = *(const float4*)(src + i);
    ushort4 r;
    r.x = f2b(v.x); r.y = f2b(v.y); r.z = f2b(v.z); r.w = f2b(v.w);
    *(ushort4*)(dst + i) = r;
  }
}

// C[m,n] = sum_k A[m,k] * W[n,k] + bias[n]
// A: (M x 1024) bf16 row-major.  W: (N x 1024) bf16 row-major.
// by>>3 selects among up to 3 weights (fused QKV); (by&7)*128 local col.
// grid = (M/128, Ntotal/128), block = 256 (4 waves, 2x2 of 64x64 wave tiles).
// OUT_F32: write float (fp32 final output) vs bf16 (intermediate).
template <bool OUT_F32>
__global__ __launch_bounds__(256) void gemm_bt(
    const unsigned short* __restrict__ A,
    const unsigned short* __restrict__ W0,
    const unsigned short* __restrict__ W1,
    const unsigned short* __restrict__ W2,
    const float* __restrict__ b0,
    const float* __restrict__ b1,
    const float* __restrict__ b2,
    void* __restrict__ Cout,
    int Nout) {
  __shared__ __align__(16) unsigned short sA[128 * 64];
  __shared__ __align__(16) unsigned short sB[128 * 64];

  const int t  = threadIdx.x;
  const int bx = blockIdx.x;
  const int by = blockIdx.y;
  const int wsel = by >> 3;
  const int nloc = (by & 7) * 128;
  const unsigned short* Wm = (wsel == 0) ? W0 : ((wsel == 1) ? W1 : W2);
  const float* bias        = (wsel == 0) ? b0 : ((wsel == 1) ? b1 : b2);

  // staging: thread t loads 8 bf16 (16B); LDS dest = base + t*16B (lane-contig)
  const int ar = t >> 3;          // 0..31
  const int ac = (t & 7) * 8;     // 0..56
  const unsigned short* gA = A  + (size_t)(bx * 128 + ar) * KK_ + ac;
  const unsigned short* gB = Wm + (size_t)(nloc + ar) * KK_ + ac;

  const int lane = t & 63;
  const int wv = t >> 6;
  const int wm = (wv >> 1) * 64;
  const int wn = (wv & 1) * 64;
  const int fr = lane & 15;          // fragment row (m or n)
  const int fk = (lane >> 4) * 8;    // fragment k offset

  f32x4 zero = {0.f, 0.f, 0.f, 0.f};
  f32x4 acc[4][4];
#pragma unroll
  for (int a = 0; a < 4; ++a)
#pragma unroll
    for (int b = 0; b < 4; ++b) acc[a][b] = zero;

  for (int k0 = 0; k0 < KK_; k0 += 64) {
#pragma unroll
    for (int it = 0; it < 4; ++it) {
      cp16(sA + t * 8 + it * 2048, gA + (size_t)it * 32 * KK_ + k0);
      cp16(sB + t * 8 + it * 2048, gB + (size_t)it * 32 * KK_ + k0);
    }
    __syncthreads();

#pragma unroll
    for (int kk = 0; kk < 64; kk += 32) {
      bf16x8 af[4], bfv[4];
#pragma unroll
      for (int mt = 0; mt < 4; ++mt)
        af[mt] = *(const bf16x8*)(sA + (wm + mt * 16 + fr) * 64 + kk + fk);
#pragma unroll
      for (int nt = 0; nt < 4; ++nt)
        bfv[nt] = *(const bf16x8*)(sB + (wn + nt * 16 + fr) * 64 + kk + fk);
#pragma unroll
      for (int mt = 0; mt < 4; ++mt)
#pragma unroll
        for (int nt = 0; nt < 4; ++nt)
          acc[mt][nt] = __builtin_amdgcn_mfma_f32_16x16x32_bf16(
              af[mt], bfv[nt], acc[mt][nt], 0, 0, 0);
    }
    __syncthreads();
  }

  // epilogue: C/D layout col=lane&15, row=(lane>>4)*4+r  [m89-verified]
  const int cc = lane & 15;
  const int rq = (lane >> 4) * 4;
#pragma unroll
  for (int mt = 0; mt < 4; ++mt) {
#pragma unroll
    for (int nt = 0; nt < 4; ++nt) {
      const int gn = by * 128 + wn + nt * 16 + cc;
      const float bb = bias[nloc + wn + nt * 16 + cc];
#pragma unroll
      for (int r = 0; r < 4; ++r) {
        const int gm = bx * 128 + wm + mt * 16 + rq + r;
        const float val = acc[mt][nt][r] + bb;
        if (OUT_F32)
          ((float*)Cout)[(size_t)gm * Nout + gn] = val;
        else
          ((unsigned short*)Cout)[(size_t)gm * Nout + gn] = f2b(val);
      }
    }
  }
}

// Per (i,j) token pair: energy[qh,kh] = sum_d q[i,j,qh,d]*k[j,i,kh,d];
// softmax over qh (axis=2) per kh; /32; out[a,:] = sum_l att[a,l]*v[i,j,l,:].
// One 256-thread block per pair.
__global__ __launch_bounds__(256) void attn_kernel(
    const unsigned short* __restrict__ qkv,  // (65536, 3072) = [q|k|v] bf16
    unsigned short* __restrict__ ao) {       // (65536, 1024) bf16
  __shared__ float sq[16 * 68];   // stride 68: 16B-aligned rows, <=2-way banks
  __shared__ float sk[16 * 68];
  __shared__ float sv[16 * 68];
  __shared__ float se[16 * 17];
  __shared__ float satt[16 * 17];
  __shared__ float smax[16];
  __shared__ float sscale[16];

  const int t = threadIdx.x;
  const int b = blockIdx.x;
  const int i = b >> 8;
  const int j = b & 255;

  const size_t rq = (size_t)b * 3072;
  const size_t rk = (size_t)(j * 256 + i) * 3072 + 1024;
  const size_t rv = rq + 2048;

  const ushort4 uq = ((const ushort4*)(qkv + rq))[t];
  const ushort4 uk = ((const ushort4*)(qkv + rk))[t];
  const ushort4 uv = ((const ushort4*)(qkv + rv))[t];

  const int h  = t >> 4;         // head 0..15
  const int d0 = (t & 15) * 4;   // dim offset 0..60
  {
    float* p = sq + h * 68 + d0;
    p[0] = b2f(uq.x); p[1] = b2f(uq.y); p[2] = b2f(uq.z); p[3] = b2f(uq.w);
    p = sk + h * 68 + d0;
    p[0] = b2f(uk.x); p[1] = b2f(uk.y); p[2] = b2f(uk.z); p[3] = b2f(uk.w);
    p = sv + h * 68 + d0;
    p[0] = b2f(uv.x); p[1] = b2f(uv.y); p[2] = b2f(uv.z); p[3] = b2f(uv.w);
  }
  __syncthreads();

  // energy: thread (qh=t>>4, kh=t&15)
  const int qh = h;
  const int kh = t & 15;
  float e = 0.f;
  {
    const float4* qr = (const float4*)(sq + qh * 68);
    const float4* kr = (const float4*)(sk + kh * 68);
#pragma unroll
    for (int c = 0; c < 16; ++c) {
      const float4 a = qr[c];
      const float4 bb = kr[c];
      e += a.x * bb.x + a.y * bb.y + a.z * bb.z + a.w * bb.w;
    }
  }
  se[qh * 17 + kh] = e;
  __syncthreads();

  // softmax over qh (column) for each kh; post-softmax scale 1/32
  if (t < 16) {
    float m = -1e30f;
#pragma unroll
    for (int q = 0; q < 16; ++q) m = fmaxf(m, se[q * 17 + t]);
    float s = 0.f;
#pragma unroll
    for (int q = 0; q < 16; ++q) s += __expf(se[q * 17 + t] - m);
    smax[t] = m;
    sscale[t] = 1.0f / (32.0f * s);
  }
  __syncthreads();
  satt[qh * 17 + kh] = __expf(e - smax[kh]) * sscale[kh];
  __syncthreads();

  // out[a, d0..d0+3] = sum_l att[a,l] * v[l, d0..d0+3];  a = t>>4
  float o0 = 0.f, o1 = 0.f, o2 = 0.f, o3 = 0.f;
#pragma unroll
  for (int l = 0; l < 16; ++l) {
    const float w = satt[qh * 17 + l];
    const float4 vv = *(const float4*)(sv + l * 68 + d0);
    o0 += w * vv.x; o1 += w * vv.y; o2 += w * vv.z; o3 += w * vv.w;
  }
  ushort4 r;
  r.x = f2b(o0); r.y = f2b(o1); r.z = f2b(o2); r.w = f2b(o3);
  ((ushort4*)(ao + (size_t)b * 1024))[t] = r;  // flat elem 4t = h*64+(t&15)*4
}

extern "C" void kernel_launch(void* const* d_in, const int* in_sizes, int n_in,
                              void* d_out, int out_size, void* d_ws, size_t ws_size,
                              hipStream_t stream) {
  const float* x  = (const float*)d_in[0];
  const float* Wq = (const float*)d_in[1];
  const float* bq = (const float*)d_in[2];
  const float* Wk = (const float*)d_in[3];
  const float* bk = (const float*)d_in[4];
  const float* Wv = (const float*)d_in[5];
  const float* bv = (const float*)d_in[6];
  const float* Wp = (const float*)d_in[7];
  const float* bp = (const float*)d_in[8];
  float* out = (float*)d_out;

  // Workspace layout (bf16 = ushort):
  //   qkv     : 65536 x 3072            = 402,653,184 B
  //   ao      : 65536 x 1024            = 134,217,728 B
  //   Wqkv_bf : 3072 x 1024 (q|k|v)     =   6,291,456 B
  //   Wp_bf   : 1024 x 1024             =   2,097,152 B   (total ~545 MB)
  unsigned short* qkv     = (unsigned short*)d_ws;
  unsigned short* ao      = qkv + (size_t)65536 * 3072;
  unsigned short* Wqkv_bf = ao  + (size_t)65536 * 1024;
  unsigned short* Wp_bf   = Wqkv_bf + (size_t)3072 * 1024;
  // x_bf16 (134 MB) lives in d_out (268 MB fp32); overwritten by final GEMM.
  unsigned short* x_bf = (unsigned short*)d_out;

  const int NX = 65536 * 1024;  // x elements
  const int NW = 1024 * 1024;   // one weight matrix

  cvt_f32_bf16<<<NX / 1024, 256, 0, stream>>>(x, x_bf, NX);
  cvt_f32_bf16<<<NW / 1024, 256, 0, stream>>>(Wq, Wqkv_bf, NW);
  cvt_f32_bf16<<<NW / 1024, 256, 0, stream>>>(Wk, Wqkv_bf + (size_t)NW, NW);
  cvt_f32_bf16<<<NW / 1024, 256, 0, stream>>>(Wv, Wqkv_bf + (size_t)2 * NW, NW);
  cvt_f32_bf16<<<NW / 1024, 256, 0, stream>>>(Wp, Wp_bf, NW);

  // fused QKV projection: (65536x1024) @ [Wq;Wk;Wv]^T -> qkv (65536x3072) bf16
  gemm_bt<false><<<dim3(512, 24), dim3(256), 0, stream>>>(
      x_bf, Wqkv_bf, Wqkv_bf + (size_t)NW, Wqkv_bf + (size_t)2 * NW,
      bq, bk, bv, (void*)qkv, 3072);
  // per-pair head-vs-head attention
  attn_kernel<<<dim3(65536), dim3(256), 0, stream>>>(qkv, ao);
  // output projection: (65536x1024) @ Wp^T -> d_out (fp32)
  gemm_bt<true><<<dim3(512, 8), dim3(256), 0, stream>>>(
      ao, Wp_bf, Wp_bf, Wp_bf, bp, bp, bp, (void*)out, 1024);
}